// Round 3
// baseline (409.457 us; speedup 1.0000x reference)
//
#include <hip/hip_runtime.h>
#include <hip/hip_fp16.h>

#define NB     4
#define H      512
#define W      512
#define ITERS  30
#define K      4             // max iterations fused per dispatch
#define TOLF   1e-05f
#define TOTAL  (NB*H*W*3)    // 3,145,728
#define BLK    512
#define NWAVES (BLK/64)      // 8
#define NBLKS  1024          // 4 images x 16x16 tiles of 32x32
#define HALO   8
#define EXT    48            // 32 + 2*HALO
#define LRS    48
#define LPS    (48*48)       // 2304
#define RRS    48            // rbt row stride (halfs)
#define RPS    (46*48)       // 2208 (46 rows)
#define NQ1    552           // stage-1 quads: 46 rows x 12 quad-cols (4 px each)
#define NP2    968           // stage-2 pairs: 44 rows x 22 pair-cols
#define S2S    2             // ceil(NP2/BLK)
#define TBIG   1000000

__device__ __forceinline__ int refl(int v, int n) {
    if (v < 0)  return -v;
    if (v >= n) return 2 * n - 2 - v;
    return v;
}

// f32 accumulate directly from f16 operand (no separate v_cvt): acc += f16(h2)*w
__device__ __forceinline__ void fmix_l(float& acc, unsigned h2, float w) {
    asm("v_fma_mix_f32 %0, %1, %2, %0 op_sel:[0,0,0] op_sel_hi:[1,0,0]"
        : "+v"(acc) : "v"(h2), "v"(w));
}
__device__ __forceinline__ void fmix_h(float& acc, unsigned h2, float w) {
    asm("v_fma_mix_f32 %0, %1, %2, %0 op_sel:[1,0,0] op_sel_hi:[1,0,0]"
        : "+v"(acc) : "v"(h2), "v"(w));
}

// Vectorized row staging: each row's in-image x-span is NF4 aligned float4s.
// y-reflection folded into refl(gy) => no row-mirror fixups needed anywhere.
template<int NF4>
__device__ __forceinline__ void stage_rows(float* lat, const float* s_n,
                                           int tid, int ty0, int xlo, int jofs) {
    for (int u = tid; u < EXT * NF4; u += BLK) {
        const int i = u / NF4, q = u - i * NF4;
        const int gy = refl(ty0 - HALO + i, H);
        const float4 v = *(const float4*)(s_n + ((size_t)gy * W + xlo) * 3 + 4 * q);
        const int f = 4 * q;
        int j = jofs + f / 3;
        int c = f - 3 * (f / 3);
        const int ib = i * LRS;
        const float vv[4] = {v.x, v.y, v.z, v.w};
        #pragma unroll
        for (int e = 0; e < 4; ++e) {
            lat[c * LPS + ib + j] = vv[e];
            if (++c == 3) { c = 0; ++j; }
        }
    }
}

// Stage-1 conv body as a MACRO (no lambda, no pointer params): operand array P
// is only ever indexed with compile-time constants => SROA keeps it in VGPRs.
// (R16 lesson: passing the array through a lambda pointer sent it to scratch —
// WRITE_SIZE +6 MB, net regression.)
#define S1CONV(LO, RO, P)                                                     \
    do {                                                                      \
        _Pragma("unroll")                                                     \
        for (int c = 0; c < 3; ++c) {                                         \
            const float* lc = &lat[c * LPS + (LO)];                           \
            const float4 Fm = *(const float4*)(lc - LRS - 1);                 \
            const float2 Gm = *(const float2*)(lc - LRS + 3);                 \
            const float4 Fc = *(const float4*)(lc - 1);                       \
            const float2 Gc = *(const float2*)(lc + 3);                       \
            const float4 Fp = *(const float4*)(lc + LRS - 1);                 \
            const float2 Gp = *(const float2*)(lc + LRS + 3);                 \
            const float sx = Fm.x + Fp.x, sy = Fm.y + Fp.y;                   \
            const float sz = Fm.z + Fp.z, sw = Fm.w + Fp.w;                   \
            const float sgx = Gm.x + Gp.x, sgy = Gm.y + Gp.y;                 \
            const float w0 = k0w[c][0], w1 = k0w[c][1], w2 = k0w[c][2];       \
            const float m0 = k1w[c][0], m1 = k1w[c][1], m2 = k1w[c][2];       \
            float a0 = fmaf(w2, sz, fmaf(w1, sy, w0 * sx));                   \
            a0 = fmaf(m2, Fc.z, fmaf(m1, Fc.y, fmaf(m0, Fc.x, a0)));          \
            float a1 = fmaf(w2, sw, fmaf(w1, sz, w0 * sy));                   \
            a1 = fmaf(m2, Fc.w, fmaf(m1, Fc.z, fmaf(m0, Fc.y, a1)));          \
            float a2 = fmaf(w2, sgx, fmaf(w1, sw, w0 * sz));                  \
            a2 = fmaf(m2, Gc.x, fmaf(m1, Fc.w, fmaf(m0, Fc.z, a2)));          \
            float a3 = fmaf(w2, sgy, fmaf(w1, sgx, w0 * sw));                 \
            a3 = fmaf(m2, Gc.y, fmaf(m1, Gc.x, fmaf(m0, Fc.w, a3)));          \
            const float r0 = P[c]     * __builtin_amdgcn_rcpf(a0);            \
            const float r1 = P[3 + c] * __builtin_amdgcn_rcpf(a1);            \
            const float r2 = P[6 + c] * __builtin_amdgcn_rcpf(a2);            \
            const float r3 = P[9 + c] * __builtin_amdgcn_rcpf(a3);            \
            uint2 Wv;                                                         \
            Wv.x = __builtin_bit_cast(unsigned, __floats2half2_rn(r0, r1));   \
            Wv.y = __builtin_bit_cast(unsigned, __floats2half2_rn(r2, r3));   \
            *(uint2*)&rbt[c * RPS + (RO)] = Wv;                               \
        }                                                                     \
    } while (0)

// One dispatch = up to K=4 fused RL iterations on a 32x32 tile, halo-8.
// R17 = R15 structure (380.6 us, best verified) + the safe subset of R16:
//  - stage-2 PAIRS restored verbatim (R16's quad b64 reads used only even
//    bank-pairs: conflicts 3.0M -> 4.6M; pairs are ~2-way = free).
//  - inp hoist for up=0 via macro/local-array (registers, not scratch).
//  - single 8B rbt store kept (8B-aligned, fewer LDS ops).
__global__ __launch_bounds__(BLK, 8) void rl_group(
    const float* __restrict__ inputs,
    const float* __restrict__ gk,
    const float* __restrict__ gkf,
    const float* __restrict__ src,       // latent at group start
    const float* __restrict__ src_prev,  // latent at PREVIOUS group start
    float* __restrict__ dst,
    float* __restrict__ part,            // [30][1024] iteration partials
    int g)                               // 0..7 compute, 8 fixup
{
    __shared__ float  lat[3 * LPS];      // 27648 B
    __shared__ __half rbt[3 * RPS];      // 13248 B
    __shared__ float  wred[NWAVES];      // 32 B
    __shared__ int    s_tstar;           // 4 B   (total 40932 <= 40960)

    const int tid  = threadIdx.x;
    const int lane = tid & 63;
    const int wid  = tid >> 6;
    const int b    = blockIdx.x;
    const int n    = b >> 8;
    const int rtile= b & 255;
    const int ty0  = (rtile >> 4) << 5;
    const int tx0  = (rtile & 15) << 5;
    const bool xe0 = (tx0 == 0), xe1 = (tx0 + 32 == W);
    const size_t nbase = (size_t)n * (H * W * 3);
    const float* inp_n = inputs + nbase;

    const int base      = (4 * g < ITERS) ? 4 * g : ITERS;
    const int prev_base = (g > 0) ? 4 * (g - 1) : 0;

    // ---- deterministic scan: first firing iteration among prior groups ----
    int tstar = TBIG;
    if (g > 0) {
        const int tmax = base;
        if (tid == 0) s_tstar = TBIG;
        __syncthreads();
        for (int t = wid; t < tmax; t += NWAVES) {
            double a = 0.0;
            for (int q = lane; q < NBLKS; q += 64)
                a += (double)part[t * NBLKS + q];
            #pragma unroll
            for (int off = 32; off; off >>= 1) a += __shfl_down(a, off, 64);
            if (lane == 0) {
                const float mean = (float)(a / (double)TOTAL);
                if (fabsf(1.0f - mean) < TOLF) atomicMin(&s_tstar, t);
            }
        }
        __syncthreads();
        tstar = s_tstar;
    }

    // ---- mode decision (block-uniform, identical across all blocks) ----
    int m;
    const float* lsrc;
    bool wr_part;
    if (g == 0) {
        m = K; lsrc = src; wr_part = true;
    } else if (tstar >= base) {
        if (g == 8) return;
        m = (ITERS - base < K) ? (ITERS - base) : K;
        lsrc = src; wr_part = true;
    } else if (tstar >= prev_base) {
        m = tstar - prev_base + 1; lsrc = src_prev; wr_part = false;
    } else {
        if (g == 8) return;
        for (int p = tid; p < 768; p += BLK) {
            const int i = p / 24, q = p - i * 24;
            const size_t o = nbase + ((size_t)(ty0 + i) * W + tx0) * 3 + 4 * q;
            *(float4*)(dst + o) = *(const float4*)(src + o);
        }
        return;
    }

    // ---- hoisted kernel weights (uniform -> SGPR). dy rows 0 == 2. ----
    float k0w[3][3], k1w[3][3], f0w[3][3], f1w[3][3];
    #pragma unroll
    for (int c = 0; c < 3; ++c) {
        #pragma unroll
        for (int dx = 0; dx < 3; ++dx) {
            k0w[c][dx] = gk [(0 + dx) * 3 + c];
            k1w[c][dx] = gk [(3 + dx) * 3 + c];
            f0w[c][dx] = gkf[(0 + dx) * 3 + c];
            f1w[c][dx] = gkf[(3 + dx) * 3 + c];
        }
    }

    // ---- stage-1 quad metadata ----
    // quad q: i = q/12 + 1 in [1,47), j = 4*(q%12) + 1 (== 1 mod 4)
    // up=0 (q = tid < 512 < NQ1): always valid; inp values hoisted into pv[]
    //   (local array, constant indices only => VGPRs).
    // up=1 (q = tid + 512 < 552): tids 0..39; inp loaded per-iter.
    int q1lat0, q1rb0, q1mrg0;
    float pv[12];
    {
        const int q = tid;
        const int i = q / 12 + 1;
        const int j = 4 * (q - (i - 1) * 12) + 1;
        q1lat0 = i * LRS + j;
        q1rb0  = (i - 1) * RRS + (j - 1);
        const int vm = min(i - 1, 46 - i);
        int cm = min(j - 1, 46 - j);
        cm = max(cm, min(j,     45 - j));
        cm = max(cm, min(j + 1, 44 - j));
        cm = max(cm, min(j + 2, 43 - j));
        q1mrg0 = min(vm, cm);
        const int ry = refl(ty0 - HALO + i, H);
        const int o0 = (ry * W + refl(tx0 - HALO + j,     W)) * 3;
        const int o1 = (ry * W + refl(tx0 - HALO + j + 1, W)) * 3;
        const int o2 = (ry * W + refl(tx0 - HALO + j + 2, W)) * 3;
        const int o3 = (ry * W + refl(tx0 - HALO + j + 3, W)) * 3;
        #pragma unroll
        for (int c = 0; c < 3; ++c) {
            pv[c]     = inp_n[o0 + c];
            pv[3 + c] = inp_n[o1 + c];
            pv[6 + c] = inp_n[o2 + c];
            pv[9 + c] = inp_n[o3 + c];
        }
    }
    int q1lat1 = 0, q1rb1 = 0, q1mrg1 = -1;
    int q1o0_1 = 0, q1o1_1 = 0, q1o2_1 = 0, q1o3_1 = 0;
    if (tid + BLK < NQ1) {
        const int q = tid + BLK;
        const int i = q / 12 + 1;
        const int j = 4 * (q - (i - 1) * 12) + 1;
        q1lat1 = i * LRS + j;
        q1rb1  = (i - 1) * RRS + (j - 1);
        const int vm = min(i - 1, 46 - i);
        int cm = min(j - 1, 46 - j);
        cm = max(cm, min(j,     45 - j));
        cm = max(cm, min(j + 1, 44 - j));
        cm = max(cm, min(j + 2, 43 - j));
        q1mrg1 = min(vm, cm);
        const int ry = refl(ty0 - HALO + i, H);
        q1o0_1 = (ry * W + refl(tx0 - HALO + j,     W)) * 3;
        q1o1_1 = (ry * W + refl(tx0 - HALO + j + 1, W)) * 3;
        q1o2_1 = (ry * W + refl(tx0 - HALO + j + 2, W)) * 3;
        q1o3_1 = (ry * W + refl(tx0 - HALO + j + 3, W)) * 3;
    }

    // ---- fixed stage-2 pair metadata (verbatim R15, RRS=48) ----
    // pair q: i = q/22 + 2 in [2,46), j = 2*(q%22) + 2 (even)
    int s2lat[S2S], s2rb[S2S], s2mrg[S2S], s2msk[S2S];
    #pragma unroll
    for (int up = 0; up < S2S; ++up) {
        const int q = tid + up * BLK;
        s2mrg[up] = -1; s2msk[up] = 0;
        if (q < NP2) {
            const int i = q / 22 + 2;
            const int j = 2 * (q - (i - 2) * 22) + 2;
            s2lat[up] = i * LRS + j;
            s2rb[up]  = (i - 2) * RRS + (j - 2);
            int mg = i - 2;
            mg = min(mg, 45 - i); mg = min(mg, j - 2); mg = min(mg, 44 - j);
            s2mrg[up] = mg;
            const bool iok = ((unsigned)(i - HALO) < 32u);
            s2msk[up] = (iok && ((unsigned)(j - HALO) < 32u) ? 1 : 0)
                      | (iok && ((unsigned)(j + 1 - HALO) < 32u) ? 2 : 0);
        }
    }

    // ---- stage 48x48 latent tile: float4 rows, refl(gy) per row ----
    const float* s_n = lsrc + nbase;
    if (!xe0 && !xe1) {
        stage_rows<36>(lat, s_n, tid, ty0, tx0 - HALO, 0);
    } else {
        stage_rows<30>(lat, s_n, tid, ty0, xe0 ? 0 : tx0 - HALO, xe0 ? HALO : 0);
    }
    __syncthreads();

    // ---- x-mirror column fixup (only x-edge tiles; y handled in staging) ----
    if (xe0 | xe1) {
        if (xe0) {
            for (int p = tid; p < 3 * EXT * HALO; p += BLK) {
                const int c = p / (EXT * HALO), rr = p - c * (EXT * HALO);
                const int i = rr / HALO, j = rr - i * HALO;
                lat[c * LPS + i * LRS + j] = lat[c * LPS + i * LRS + (16 - j)];
            }
        } else {
            for (int p = tid; p < 3 * EXT * HALO; p += BLK) {
                const int c = p / (EXT * HALO), rr = p - c * (EXT * HALO);
                const int i = rr / HALO, j2 = rr - i * HALO;
                lat[c * LPS + i * LRS + 40 + j2] = lat[c * LPS + i * LRS + (38 - j2)];
            }
        }
        __syncthreads();
    }

    // ---- fused sub-iterations (2 barriers each) ----
    #pragma unroll
    for (int s = 0; s < K; ++s) {
        if (s >= m) break;

        // stage 1: rb = inp * rcp(conv(lat, k)) — span-4 quads, dy-symmetric:
        // rows i-1 and i+1 pre-summed (gk row0 == row2), 6 mult/px.
        if (2 * s <= q1mrg0) S1CONV(q1lat0, q1rb0, pv);
        if (2 * s <= q1mrg1) {
            float pw[12];
            #pragma unroll
            for (int c = 0; c < 3; ++c) {
                pw[c]     = inp_n[q1o0_1 + c];
                pw[3 + c] = inp_n[q1o1_1 + c];
                pw[6 + c] = inp_n[q1o2_1 + c];
                pw[9 + c] = inp_n[q1o3_1 + c];
            }
            S1CONV(q1lat1, q1rb1, pw);
        }
        __syncthreads();

        // stage 2: e = conv(rb, kf); lat *= e; esum over interior.
        // dy rows 0+2 pre-summed in fp16 (v_pk_add_f16, gkf row0 == row2),
        // then 12 v_fma_mix_f32 per channel: f32 accumulation, no cvt chain.
        float esum = 0.f;
        #pragma unroll
        for (int up = 0; up < S2S; ++up) {
            if (2 * s <= s2mrg[up]) {
                const int ro = s2rb[up];
                const int lo = s2lat[up];
                const int mk = s2msk[up];
                float te0 = 0.f, te1 = 0.f;
                #pragma unroll
                for (int c = 0; c < 3; ++c) {
                    const __half2* R0 = (const __half2*)&rbt[c * RPS + ro];
                    const __half2* R1 = (const __half2*)&rbt[c * RPS + ro + RRS];
                    const __half2* R2 = (const __half2*)&rbt[c * RPS + ro + 2 * RRS];
                    const __half2 r00 = R0[0], r01 = R0[1];
                    const __half2 r10 = R1[0], r11 = R1[1];
                    const __half2 r20 = R2[0], r21 = R2[1];
                    const unsigned s0 = __builtin_bit_cast(unsigned, __hadd2(r00, r20));
                    const unsigned s1 = __builtin_bit_cast(unsigned, __hadd2(r01, r21));
                    const unsigned m0 = __builtin_bit_cast(unsigned, r10);
                    const unsigned m1 = __builtin_bit_cast(unsigned, r11);
                    const float w0 = f0w[c][0], w1 = f0w[c][1], w2 = f0w[c][2];
                    const float v0 = f1w[c][0], v1 = f1w[c][1], v2 = f1w[c][2];
                    float e0 = 0.f, e1 = 0.f;
                    fmix_l(e0, s0, w0); fmix_h(e0, s0, w1); fmix_l(e0, s1, w2);
                    fmix_l(e0, m0, v0); fmix_h(e0, m0, v1); fmix_l(e0, m1, v2);
                    fmix_h(e1, s0, w0); fmix_l(e1, s1, w1); fmix_h(e1, s1, w2);
                    fmix_h(e1, m0, v0); fmix_l(e1, m1, v1); fmix_h(e1, m1, v2);
                    float2* Lp = (float2*)&lat[c * LPS + lo];
                    float2 lv = *Lp;
                    lv.x *= e0; lv.y *= e1;
                    *Lp = lv;
                    te0 += e0; te1 += e1;
                }
                esum += (mk & 1) ? te0 : 0.f;
                esum += (mk & 2) ? te1 : 0.f;
            }
        }
        if (wr_part) {
            #pragma unroll
            for (int off = 32; off; off >>= 1) esum += __shfl_down(esum, off, 64);
            if (lane == 0) wred[wid] = esum;
        }
        __syncthreads();     // lat writes done AND wred ready
        if (wr_part && tid == 0) {
            float t = 0.f;
            #pragma unroll
            for (int w2 = 0; w2 < NWAVES; ++w2) t += wred[w2];
            part[(base + s) * NBLKS + b] = t;
        }
    }

    // ---- write interior [8,40)^2 to dst as float4 (96 floats/row = 24 f4) ----
    for (int u = tid; u < 768; u += BLK) {
        const int i = u / 24, q = u - i * 24;
        const int f = 4 * q;
        int jj = HALO + f / 3;
        int c = f - 3 * (f / 3);
        const int ib = (i + HALO) * LRS;
        float vv[4];
        #pragma unroll
        for (int e = 0; e < 4; ++e) {
            vv[e] = lat[c * LPS + ib + jj];
            if (++c == 3) { c = 0; ++jj; }
        }
        *(float4*)(dst + nbase + ((size_t)(ty0 + i) * W + tx0) * 3 + f) =
            make_float4(vv[0], vv[1], vv[2], vv[3]);
    }
}

extern "C" void kernel_launch(void* const* d_in, const int* in_sizes, int n_in,
                              void* d_out, int out_size, void* d_ws, size_t ws_size,
                              hipStream_t stream) {
    const float* inputs = (const float*)d_in[0];
    const float* gk     = (const float*)d_in[1];
    const float* gkf    = (const float*)d_in[2];
    float* out = (float*)d_out;

    // ws: [0 .. 128KB) iteration partials [30][1024] | buffer A | buffer B
    char* ws = (char*)d_ws;
    float* part = (float*)ws;
    float* A    = (float*)(ws + 131072);
    float* Bb   = (float*)(ws + 131072 + (size_t)TOTAL * sizeof(float));

    // period-3 schedule; X[g] = latent at start of group g. X[8] = out.
    const float* X[9] = { inputs, A, out, Bb, A, out, Bb, A, out };

    for (int g = 0; g < 9; ++g) {
        const float* s  = X[(g == 8) ? 7 : g];
        const float* sp = X[(g == 0) ? 0 : g - 1];
        float*       d  = (float*)((g == 8) ? X[8] : X[g + 1]);
        rl_group<<<NBLKS, BLK, 0, stream>>>(inputs, gk, gkf, s, sp, d, part, g);
    }
}

// Round 4
// 336.964 us; speedup vs baseline: 1.2151x; 1.2151x over previous
//
#include <hip/hip_runtime.h>
#include <hip/hip_fp16.h>

#define NB     4
#define H      512
#define W      512
#define ITERS  30
#define K      4             // max iterations fused per dispatch
#define TOLF   1e-05f
#define TOTAL  (NB*H*W*3)    // 3,145,728
#define BLK    512
#define NWAVES (BLK/64)      // 8
#define NBLKS  1024          // 4 images x 16x16 tiles of 32x32
#define HALO   8
#define EXT    48            // 32 + 2*HALO
#define LRS    48
#define LPS    (48*48)       // 2304
#define RRS    48            // rbt row stride (halfs)
#define RPS    (46*48)       // 2208 (46 rows)
#define NQ1    552           // stage-1 quads: 46 rows x 12 quad-cols (4 px each)
#define NP2    968           // stage-2 pairs: 44 rows x 22 pair-cols
#define S2S    2             // ceil(NP2/BLK)
#define TBIG   1000000

__device__ __forceinline__ int refl(int v, int n) {
    if (v < 0)  return -v;
    if (v >= n) return 2 * n - 2 - v;
    return v;
}

// f32 accumulate directly from f16 operand (no separate v_cvt): acc += f16(h2)*w
__device__ __forceinline__ void fmix_l(float& acc, unsigned h2, float w) {
    asm("v_fma_mix_f32 %0, %1, %2, %0 op_sel:[0,0,0] op_sel_hi:[1,0,0]"
        : "+v"(acc) : "v"(h2), "v"(w));
}
__device__ __forceinline__ void fmix_h(float& acc, unsigned h2, float w) {
    asm("v_fma_mix_f32 %0, %1, %2, %0 op_sel:[1,0,0] op_sel_hi:[1,0,0]"
        : "+v"(acc) : "v"(h2), "v"(w));
}

// Vectorized row staging: each row's in-image x-span is NF4 aligned float4s.
// y-reflection folded into refl(gy) => no row-mirror fixups needed anywhere.
template<int NF4>
__device__ __forceinline__ void stage_rows(float* lat, const float* s_n,
                                           int tid, int ty0, int xlo, int jofs) {
    for (int u = tid; u < EXT * NF4; u += BLK) {
        const int i = u / NF4, q = u - i * NF4;
        const int gy = refl(ty0 - HALO + i, H);
        const float4 v = *(const float4*)(s_n + ((size_t)gy * W + xlo) * 3 + 4 * q);
        const int f = 4 * q;
        int j = jofs + f / 3;
        int c = f - 3 * (f / 3);
        const int ib = i * LRS;
        const float vv[4] = {v.x, v.y, v.z, v.w};
        #pragma unroll
        for (int e = 0; e < 4; ++e) {
            lat[c * LPS + ib + j] = vv[e];
            if (++c == 3) { c = 0; ++j; }
        }
    }
}

// Stage lat from SRCP and apply x-mirror fixup. Contains its own barriers.
#define STAGE_AND_FIX(SRCP)                                                    \
    do {                                                                       \
        const float* s_n_ = (SRCP) + nbase;                                    \
        if (!xe0 && !xe1)                                                      \
            stage_rows<36>(lat, s_n_, tid, ty0, tx0 - HALO, 0);                \
        else                                                                   \
            stage_rows<30>(lat, s_n_, tid, ty0, xe0 ? 0 : tx0 - HALO,          \
                           xe0 ? HALO : 0);                                    \
        __syncthreads();                                                       \
        if (xe0 | xe1) {                                                       \
            if (xe0) {                                                         \
                for (int p = tid; p < 3 * EXT * HALO; p += BLK) {              \
                    const int c_ = p / (EXT * HALO), rr = p - c_ * (EXT*HALO); \
                    const int i_ = rr / HALO, j_ = rr - i_ * HALO;             \
                    lat[c_ * LPS + i_ * LRS + j_] =                            \
                        lat[c_ * LPS + i_ * LRS + (16 - j_)];                  \
                }                                                              \
            } else {                                                           \
                for (int p = tid; p < 3 * EXT * HALO; p += BLK) {              \
                    const int c_ = p / (EXT * HALO), rr = p - c_ * (EXT*HALO); \
                    const int i_ = rr / HALO, j2 = rr - i_ * HALO;             \
                    lat[c_ * LPS + i_ * LRS + 40 + j2] =                       \
                        lat[c_ * LPS + i_ * LRS + (38 - j2)];                  \
                }                                                              \
            }                                                                  \
            __syncthreads();                                                   \
        }                                                                      \
    } while (0)

// Write interior [8,40)^2 from lat to dst as float4 (96 floats/row = 24 f4).
#define WRITE_INTERIOR()                                                       \
    do {                                                                       \
        for (int u = tid; u < 768; u += BLK) {                                 \
            const int i_ = u / 24, q_ = u - i_ * 24;                           \
            const int f_ = 4 * q_;                                             \
            int jj = HALO + f_ / 3;                                            \
            int c_ = f_ - 3 * (f_ / 3);                                        \
            const int ib = (i_ + HALO) * LRS;                                  \
            float v0_, v1_, v2_, v3_;                                          \
            v0_ = lat[c_ * LPS + ib + jj];                                     \
            if (++c_ == 3) { c_ = 0; ++jj; }                                   \
            v1_ = lat[c_ * LPS + ib + jj];                                     \
            if (++c_ == 3) { c_ = 0; ++jj; }                                   \
            v2_ = lat[c_ * LPS + ib + jj];                                     \
            if (++c_ == 3) { c_ = 0; ++jj; }                                   \
            v3_ = lat[c_ * LPS + ib + jj];                                     \
            *(float4*)(dst + nbase + ((size_t)(ty0 + i_) * W + tx0) * 3 + f_)  \
                = make_float4(v0_, v1_, v2_, v3_);                             \
        }                                                                      \
    } while (0)

// One dispatch = up to K=4 fused RL iterations on a 32x32 tile, halo-8.
// R18 = R15 (380.6 us, best verified) inner loops byte-identical; the round's
// change is dispatch-head overlap:
//  - g<8: stage the 48x48 tile from src FIRST, then run the part[] scan —
//    the scan's serial global reductions now hide under staging latency.
//    Common case (tstar >= base) uses src anyway: zero waste. Rare in-window
//    case restages from src_prev. Copy case writes interior FROM LDS.
//  - g==8 keeps scan-first (common path returns without staging).
//  - scan inner f64 chain split into 2 accumulators (same order all blocks).
// R16/R17 lessons applied: NO local-array inp hoist (scratch spill), keep
// 2x b32 rbt stores (b64 store raised bank conflicts).
__global__ __launch_bounds__(BLK, 8) void rl_group(
    const float* __restrict__ inputs,
    const float* __restrict__ gk,
    const float* __restrict__ gkf,
    const float* __restrict__ src,       // latent at group start
    const float* __restrict__ src_prev,  // latent at PREVIOUS group start
    float* __restrict__ dst,
    float* __restrict__ part,            // [30][1024] iteration partials
    int g)                               // 0..7 compute, 8 fixup
{
    __shared__ float  lat[3 * LPS];      // 27648 B
    __shared__ __half rbt[3 * RPS];      // 13248 B
    __shared__ float  wred[NWAVES];      // 32 B
    __shared__ int    s_tstar;           // 4 B   (total 40932 <= 40960)

    const int tid  = threadIdx.x;
    const int lane = tid & 63;
    const int wid  = tid >> 6;
    const int b    = blockIdx.x;
    const int n    = b >> 8;
    const int rtile= b & 255;
    const int ty0  = (rtile >> 4) << 5;
    const int tx0  = (rtile & 15) << 5;
    const bool xe0 = (tx0 == 0), xe1 = (tx0 + 32 == W);
    const size_t nbase = (size_t)n * (H * W * 3);
    const float* inp_n = inputs + nbase;

    const int base      = (4 * g < ITERS) ? 4 * g : ITERS;
    const int prev_base = (g > 0) ? 4 * (g - 1) : 0;

    // ---- stage src tile first (g<8); scan overlaps it below ----
    if (g > 0 && tid == 0) s_tstar = TBIG;
    if (g < 8) {
        STAGE_AND_FIX(src);              // contains the barrier after staging
    } else {
        __syncthreads();                 // orders s_tstar init before scan
    }

    // ---- deterministic scan: first firing iteration among prior groups ----
    int tstar = TBIG;
    if (g > 0) {
        for (int t = wid; t < base; t += NWAVES) {
            double a0 = 0.0, a1 = 0.0;
            for (int q = lane; q < NBLKS; q += 128) {
                a0 += (double)part[t * NBLKS + q];
                a1 += (double)part[t * NBLKS + q + 64];
            }
            double a = a0 + a1;
            #pragma unroll
            for (int off = 32; off; off >>= 1) a += __shfl_down(a, off, 64);
            if (lane == 0) {
                const float mean = (float)(a / (double)TOTAL);
                if (fabsf(1.0f - mean) < TOLF) atomicMin(&s_tstar, t);
            }
        }
        __syncthreads();
        tstar = s_tstar;
    }

    // ---- mode decision (block-uniform, identical across all blocks) ----
    int m;
    bool wr_part;
    if (g == 0) {
        m = K; wr_part = true;                       // lat already = src
    } else if (tstar >= base) {
        if (g == 8) return;
        m = (ITERS - base < K) ? (ITERS - base) : K;
        wr_part = true;                              // lat already = src
    } else if (tstar >= prev_base) {
        m = tstar - prev_base + 1; wr_part = false;
        STAGE_AND_FIX(src_prev);                     // restage (rare; g==8: first stage)
    } else {
        if (g == 8) return;
        WRITE_INTERIOR();                            // lat == src interior
        return;
    }

    // ---- hoisted kernel weights (uniform). dy rows 0 == 2. ----
    float k0w[3][3], k1w[3][3], f0w[3][3], f1w[3][3];
    #pragma unroll
    for (int c = 0; c < 3; ++c) {
        #pragma unroll
        for (int dx = 0; dx < 3; ++dx) {
            k0w[c][dx] = gk [(0 + dx) * 3 + c];
            k1w[c][dx] = gk [(3 + dx) * 3 + c];
            f0w[c][dx] = gkf[(0 + dx) * 3 + c];
            f1w[c][dx] = gkf[(3 + dx) * 3 + c];
        }
    }

    // ---- stage-1 quad metadata (2 slots, verbatim R15) ----
    // quad q: i = q/12 + 1 in [1,47), j = 4*(q%12) + 1 (== 1 mod 4)
    int q1lat[2], q1rb[2], q1mrg[2];
    int q1o0[2], q1o1[2], q1o2[2], q1o3[2];
    #pragma unroll
    for (int up = 0; up < 2; ++up) {
        const int q = tid + up * BLK;
        q1mrg[up] = -1;
        if (q < NQ1) {
            const int i = q / 12 + 1;
            const int j = 4 * (q - (i - 1) * 12) + 1;
            q1lat[up] = i * LRS + j;
            q1rb[up]  = (i - 1) * RRS + (j - 1);
            const int vm = min(i - 1, 46 - i);
            int cm = min(j - 1, 46 - j);
            cm = max(cm, min(j,     45 - j));
            cm = max(cm, min(j + 1, 44 - j));
            cm = max(cm, min(j + 2, 43 - j));
            q1mrg[up] = min(vm, cm);
            const int ry = refl(ty0 - HALO + i, H);
            q1o0[up] = (ry * W + refl(tx0 - HALO + j,     W)) * 3;
            q1o1[up] = (ry * W + refl(tx0 - HALO + j + 1, W)) * 3;
            q1o2[up] = (ry * W + refl(tx0 - HALO + j + 2, W)) * 3;
            q1o3[up] = (ry * W + refl(tx0 - HALO + j + 3, W)) * 3;
        }
    }

    // ---- fixed stage-2 pair metadata (verbatim R15, RRS=48) ----
    // pair q: i = q/22 + 2 in [2,46), j = 2*(q%22) + 2 (even)
    int s2lat[S2S], s2rb[S2S], s2mrg[S2S], s2msk[S2S];
    #pragma unroll
    for (int up = 0; up < S2S; ++up) {
        const int q = tid + up * BLK;
        s2mrg[up] = -1; s2msk[up] = 0;
        if (q < NP2) {
            const int i = q / 22 + 2;
            const int j = 2 * (q - (i - 2) * 22) + 2;
            s2lat[up] = i * LRS + j;
            s2rb[up]  = (i - 2) * RRS + (j - 2);
            int mg = i - 2;
            mg = min(mg, 45 - i); mg = min(mg, j - 2); mg = min(mg, 44 - j);
            s2mrg[up] = mg;
            const bool iok = ((unsigned)(i - HALO) < 32u);
            s2msk[up] = (iok && ((unsigned)(j - HALO) < 32u) ? 1 : 0)
                      | (iok && ((unsigned)(j + 1 - HALO) < 32u) ? 2 : 0);
        }
    }

    // ---- fused sub-iterations (2 barriers each, verbatim R15) ----
    #pragma unroll
    for (int s = 0; s < K; ++s) {
        if (s >= m) break;

        // stage 1: rb = inp * rcp(conv(lat, k)) — span-4 quads, dy-symmetric:
        // rows i-1 and i+1 pre-summed (gk row0 == row2), 6 mult/px.
        #pragma unroll
        for (int up = 0; up < 2; ++up) {
            if (2 * s <= q1mrg[up]) {
                const int lo = q1lat[up];
                const int ro = q1rb[up];
                #pragma unroll
                for (int c = 0; c < 3; ++c) {
                    const float p0 = inp_n[q1o0[up] + c];
                    const float p1 = inp_n[q1o1[up] + c];
                    const float p2 = inp_n[q1o2[up] + c];
                    const float p3 = inp_n[q1o3[up] + c];
                    const float* lc = &lat[c * LPS + lo];
                    const float4 Fm = *(const float4*)(lc - LRS - 1);
                    const float2 Gm = *(const float2*)(lc - LRS + 3);
                    const float4 Fc = *(const float4*)(lc - 1);
                    const float2 Gc = *(const float2*)(lc + 3);
                    const float4 Fp = *(const float4*)(lc + LRS - 1);
                    const float2 Gp = *(const float2*)(lc + LRS + 3);
                    const float sx = Fm.x + Fp.x, sy = Fm.y + Fp.y;
                    const float sz = Fm.z + Fp.z, sw = Fm.w + Fp.w;
                    const float sgx = Gm.x + Gp.x, sgy = Gm.y + Gp.y;
                    const float w0 = k0w[c][0], w1 = k0w[c][1], w2 = k0w[c][2];
                    const float m0 = k1w[c][0], m1 = k1w[c][1], m2 = k1w[c][2];
                    float a0 = fmaf(w2, sz, fmaf(w1, sy, w0 * sx));
                    a0 = fmaf(m2, Fc.z, fmaf(m1, Fc.y, fmaf(m0, Fc.x, a0)));
                    float a1 = fmaf(w2, sw, fmaf(w1, sz, w0 * sy));
                    a1 = fmaf(m2, Fc.w, fmaf(m1, Fc.z, fmaf(m0, Fc.y, a1)));
                    float a2 = fmaf(w2, sgx, fmaf(w1, sw, w0 * sz));
                    a2 = fmaf(m2, Gc.x, fmaf(m1, Fc.w, fmaf(m0, Fc.z, a2)));
                    float a3 = fmaf(w2, sgy, fmaf(w1, sgx, w0 * sw));
                    a3 = fmaf(m2, Gc.y, fmaf(m1, Gc.x, fmaf(m0, Fc.w, a3)));
                    const float r0 = p0 * __builtin_amdgcn_rcpf(a0);
                    const float r1 = p1 * __builtin_amdgcn_rcpf(a1);
                    const float r2 = p2 * __builtin_amdgcn_rcpf(a2);
                    const float r3 = p3 * __builtin_amdgcn_rcpf(a3);
                    *(__half2*)&rbt[c * RPS + ro]     = __floats2half2_rn(r0, r1);
                    *(__half2*)&rbt[c * RPS + ro + 2] = __floats2half2_rn(r2, r3);
                }
            }
        }
        __syncthreads();

        // stage 2: e = conv(rb, kf); lat *= e; esum over interior.
        // dy rows 0+2 pre-summed in fp16 (v_pk_add_f16, gkf row0 == row2),
        // then 12 v_fma_mix_f32 per channel: f32 accumulation, no cvt chain.
        float esum = 0.f;
        #pragma unroll
        for (int up = 0; up < S2S; ++up) {
            if (2 * s <= s2mrg[up]) {
                const int ro = s2rb[up];
                const int lo = s2lat[up];
                const int mk = s2msk[up];
                float te0 = 0.f, te1 = 0.f;
                #pragma unroll
                for (int c = 0; c < 3; ++c) {
                    const __half2* R0 = (const __half2*)&rbt[c * RPS + ro];
                    const __half2* R1 = (const __half2*)&rbt[c * RPS + ro + RRS];
                    const __half2* R2 = (const __half2*)&rbt[c * RPS + ro + 2 * RRS];
                    const __half2 r00 = R0[0], r01 = R0[1];
                    const __half2 r10 = R1[0], r11 = R1[1];
                    const __half2 r20 = R2[0], r21 = R2[1];
                    const unsigned s0 = __builtin_bit_cast(unsigned, __hadd2(r00, r20));
                    const unsigned s1 = __builtin_bit_cast(unsigned, __hadd2(r01, r21));
                    const unsigned m0 = __builtin_bit_cast(unsigned, r10);
                    const unsigned m1 = __builtin_bit_cast(unsigned, r11);
                    const float w0 = f0w[c][0], w1 = f0w[c][1], w2 = f0w[c][2];
                    const float v0 = f1w[c][0], v1 = f1w[c][1], v2 = f1w[c][2];
                    float e0 = 0.f, e1 = 0.f;
                    fmix_l(e0, s0, w0); fmix_h(e0, s0, w1); fmix_l(e0, s1, w2);
                    fmix_l(e0, m0, v0); fmix_h(e0, m0, v1); fmix_l(e0, m1, v2);
                    fmix_h(e1, s0, w0); fmix_l(e1, s1, w1); fmix_h(e1, s1, w2);
                    fmix_h(e1, m0, v0); fmix_l(e1, m1, v1); fmix_h(e1, m1, v2);
                    float2* Lp = (float2*)&lat[c * LPS + lo];
                    float2 lv = *Lp;
                    lv.x *= e0; lv.y *= e1;
                    *Lp = lv;
                    te0 += e0; te1 += e1;
                }
                esum += (mk & 1) ? te0 : 0.f;
                esum += (mk & 2) ? te1 : 0.f;
            }
        }
        if (wr_part) {
            #pragma unroll
            for (int off = 32; off; off >>= 1) esum += __shfl_down(esum, off, 64);
            if (lane == 0) wred[wid] = esum;
        }
        __syncthreads();     // lat writes done AND wred ready
        if (wr_part && tid == 0) {
            float t = 0.f;
            #pragma unroll
            for (int w2 = 0; w2 < NWAVES; ++w2) t += wred[w2];
            part[(base + s) * NBLKS + b] = t;
        }
    }

    // ---- write interior [8,40)^2 to dst ----
    WRITE_INTERIOR();
}

extern "C" void kernel_launch(void* const* d_in, const int* in_sizes, int n_in,
                              void* d_out, int out_size, void* d_ws, size_t ws_size,
                              hipStream_t stream) {
    const float* inputs = (const float*)d_in[0];
    const float* gk     = (const float*)d_in[1];
    const float* gkf    = (const float*)d_in[2];
    float* out = (float*)d_out;

    // ws: [0 .. 128KB) iteration partials [30][1024] | buffer A | buffer B
    char* ws = (char*)d_ws;
    float* part = (float*)ws;
    float* A    = (float*)(ws + 131072);
    float* Bb   = (float*)(ws + 131072 + (size_t)TOTAL * sizeof(float));

    // period-3 schedule; X[g] = latent at start of group g. X[8] = out.
    const float* X[9] = { inputs, A, out, Bb, A, out, Bb, A, out };

    for (int g = 0; g < 9; ++g) {
        const float* s  = X[(g == 8) ? 7 : g];
        const float* sp = X[(g == 0) ? 0 : g - 1];
        float*       d  = (float*)((g == 8) ? X[8] : X[g + 1]);
        rl_group<<<NBLKS, BLK, 0, stream>>>(inputs, gk, gkf, s, sp, d, part, g);
    }
}